// Round 16
// baseline (1349.504 us; speedup 1.0000x reference)
//
#include <hip/hip_runtime.h>
#include <stdint.h>

// Linformer CMHAttention on MI355X (gfx950).
// B=4,S=4096,C=1024,H=16,D=64,K=256. bf16 MFMA 16x16x32, fp32 accum.
// R16: occupancy experiment on gemm_qkv ONLY — gemm256_occ2: BK32, 64KB LDS
//      double-buffer -> 2 blocks/CU (16 waves/CU) so cross-block TLP hides
//      barrier drains (m97/m114 mechanism; untested by R7-R9 whose pipes all
//      used 128KB = 1 block/CU). 2-barrier/tile, vmcnt(4), R7-verified 64B-row
//      swizzle. gemm_out keeps R9 pipe (control). Rest byte-identical R15.

typedef unsigned short u16;
typedef __bf16 bf16t;
typedef bf16t bf16x8 __attribute__((ext_vector_type(8)));
typedef float f32x4 __attribute__((ext_vector_type(4)));
typedef u16 u16x8 __attribute__((ext_vector_type(8)));

#define MFMA16(a, b, c) __builtin_amdgcn_mfma_f32_16x16x32_bf16((a), (b), (c), 0, 0, 0)

__device__ __forceinline__ u16 f2bf(float f) {
  return __builtin_bit_cast(u16, (bf16t)f);
}

__device__ __forceinline__ bf16x8 ldf(const u16* p) { return *(const bf16x8*)p; }

__device__ __forceinline__ void gload16(const void* g, void* l) {
  __builtin_amdgcn_global_load_lds(
      (__attribute__((address_space(1))) void*)g,
      (__attribute__((address_space(3))) void*)l, 16, 0, 0);
}

__device__ __forceinline__ int xcd_swz(int orig, int nwg) {
  return (orig & 7) * (nwg >> 3) + (orig >> 3);
}

#define FENCE asm volatile("" ::: "memory")
#define BAR                                  \
  do {                                       \
    FENCE;                                   \
    __builtin_amdgcn_s_barrier();            \
    FENCE;                                   \
  } while (0)

// ========== R16 pipe: 256x256, BK32, 64KB LDS (2 blocks/CU) ==========
// A,B row-major stride 1024 elems. Buf p (p=t&1) at p*32768: A[256][64B] @0,
// B @16384. 16B slot s at row R holds k-chunk s^((R>>1)&3) (R7-verified;
// pre-swizzled source, linear gload dest, same XOR on read).
// Per tile t (32 tiles): stage(t+1)->buf (t+1)&1; vmcnt(4); BAR;
// 12 ds_read + 32 MFMA (setprio); BAR.
__device__ __forceinline__ void gemm256_occ2(const u16* __restrict__ A,
                                             const u16* __restrict__ B,
                                             int m0, int n0, f32x4 acc[8][4],
                                             char* smc) {
  const int tid = threadIdx.x;
  const int w = tid >> 6, l = tid & 63, g = l >> 4, r = l & 15;
  const int wr = w >> 2, wc = w & 3;
  const int gx = ((g ^ ((r >> 1) & 3)) << 4);  // read-side swizzle (bytes)

  auto stageAB = [&](int T, int buf) {
#pragma unroll
    for (int i = 0; i < 2; ++i) {
      const int G = i * 512 + tid;  // 0..1023
      const int row = G >> 2, slot = G & 3;
      const int sc = slot ^ ((row >> 1) & 3);  // pre-swizzled source chunk
      gload16((const char*)A + ((size_t)(m0 + row) * 1024 + T * 32) * 2 + sc * 16,
              smc + buf * 32768 + G * 16);
      gload16((const char*)B + ((size_t)(n0 + row) * 1024 + T * 32) * 2 + sc * 16,
              smc + buf * 32768 + 16384 + G * 16);
    }
  };

  stageAB(0, 0);
#pragma unroll 1
  for (int t = 0; t < 32; ++t) {
    const int buf = t & 1;
    stageAB(t < 31 ? t + 1 : 31, buf ^ 1);
    asm volatile("s_waitcnt vmcnt(4)" ::: "memory");  // tile t landed
    BAR;
    const char* At = smc + buf * 32768;
    const char* Bt = At + 16384;
    bf16x8 af[8], bfv[4];
#pragma unroll
    for (int n = 0; n < 4; ++n)
      bfv[n] = *(const bf16x8*)(Bt + (wc * 64 + n * 16 + r) * 64 + gx);
#pragma unroll
    for (int m = 0; m < 8; ++m)
      af[m] = *(const bf16x8*)(At + (wr * 128 + m * 16 + r) * 64 + gx);
    __builtin_amdgcn_s_setprio(1);
#pragma unroll
    for (int m = 0; m < 8; ++m)
#pragma unroll
      for (int n = 0; n < 4; ++n)
        acc[m][n] = MFMA16(af[m], bfv[n], acc[m][n]);
    __builtin_amdgcn_s_setprio(0);
    BAR;
  }
}

// ========== R9 pipe (proven, 7-half-tile prologue) — control ==========
__device__ __forceinline__ void gemm256_pipe(const u16* __restrict__ A,
                                             const u16* __restrict__ B,
                                             int m0, int n0, int sA1, int sB1,
                                             int s0, int kt0, f32x4 acc[8][4],
                                             char* smc) {
  const int tid = threadIdx.x;
  const int w = tid >> 6, l = tid & 63, g = l >> 4, r = l & 15;
  const int wr = w >> 2, wc = w & 3;
  const int lrow = l >> 2;
  const int ksw = (((l & 3) ^ ((l >> 3) & 3)) << 4);
  const int gx = ((g ^ ((r >> 1) & 3)) << 4);

  auto stage = [&](const u16* Base, int r0, int s1, int T, int ch, int ldsoff) {
#pragma unroll
    for (int i = 0; i < 2; ++i) {
      const int row = r0 + (w * 2 + i) * 16 + lrow;
      const size_t eoff = (size_t)(row >> 6) * s1 + (size_t)(row & 63) * s0;
      gload16((const char*)Base + eoff * 2 + ((kt0 + T) * 64 + ch * 32) * 2 + ksw,
              smc + ldsoff + (w * 2 + i) * 1024);
    }
  };

#define RD_B(dst, Bt)                                                     \
  _Pragma("unroll") for (int n = 0; n < 4; ++n)                           \
      dst[n] = *(const bf16x8*)((Bt) + (wc * 64 + n * 16 + r) * 64 + gx);
#define RD_A(dst, At, MH)                                                 \
  _Pragma("unroll") for (int m = 0; m < 4; ++m)                           \
      dst[m] = *(const bf16x8*)((At) + (wr * 128 + (MH)*64 + m * 16 + r) * 64 + gx);
#define QUAD(MH)                                                          \
  __builtin_amdgcn_s_setprio(1);                                          \
  _Pragma("unroll") for (int m = 0; m < 4; ++m)                           \
      _Pragma("unroll") for (int n = 0; n < 4; ++n)                       \
          acc[(MH)*4 + m][n] = MFMA16(af[m], bfv[n], acc[(MH)*4 + m][n]); \
  __builtin_amdgcn_s_setprio(0);

  stage(B, n0, sB1, 0, 0, 0 + 32768);      // B0(0)
  stage(A, m0, sA1, 0, 0, 0 + 0);          // A0(0)
  stage(B, n0, sB1, 0, 1, 0 + 49152);      // B1(0)
  stage(A, m0, sA1, 0, 1, 0 + 16384);      // A1(0)
  stage(B, n0, sB1, 1, 0, 65536 + 32768);  // B0(1)
  stage(A, m0, sA1, 1, 0, 65536 + 0);      // A0(1)
  stage(B, n0, sB1, 1, 1, 65536 + 49152);  // B1(1)
  asm volatile("s_waitcnt vmcnt(10)" ::: "memory");
  BAR;

  for (int t = 0; t < 16; ++t) {
    const int buf = (t & 1) << 16, nb = buf ^ 65536;
    const int T1 = t < 15 ? t + 1 : 15;
    const int T2 = t < 14 ? t + 2 : 15;
    bf16x8 af[4], bfv[4];
    const char* At0 = smc + buf;
    const char* At1 = smc + buf + 16384;
    const char* Bt0 = smc + buf + 32768;
    const char* Bt1 = smc + buf + 49152;

    RD_B(bfv, Bt0)
    RD_A(af, At0, 0)
    stage(A, m0, sA1, T1, 1, nb + 16384);
    BAR;
    QUAD(0)
    BAR;
    RD_A(af, At0, 1)
    stage(B, n0, sB1, T2, 0, buf + 32768);
    asm volatile("s_waitcnt vmcnt(10)" ::: "memory");
    BAR;
    QUAD(1)
    BAR;
    RD_B(bfv, Bt1)
    RD_A(af, At1, 0)
    stage(A, m0, sA1, T2, 0, buf + 0);
    BAR;
    QUAD(0)
    BAR;
    RD_A(af, At1, 1)
    stage(B, n0, sB1, T2, 1, buf + 49152);
    asm volatile("s_waitcnt vmcnt(10)" ::: "memory");
    BAR;
    QUAD(1)
    BAR;
  }
#undef RD_B
#undef RD_A
#undef QUAD
}

// ---------------- f32 -> bf16 conversion: x + small weights only ------------
__global__ __launch_bounds__(256) void cvt_all(
    const float* __restrict__ x, const float* __restrict__ Wq,
    const float* __restrict__ Wk, const float* __restrict__ Wv,
    const float* __restrict__ Wo, u16* __restrict__ xb, u16* __restrict__ wqkv,
    u16* __restrict__ wob) {
  const int i = blockIdx.x * 256 + threadIdx.x;
  const float* s;
  u16* d;
  int off;
  if (i < 2097152) {
    s = x; d = xb; off = i;
  } else {
    const int j = i - 2097152, sel = j >> 17;
    off = j & 131071;
    if (sel == 0)      { s = Wq; d = wqkv; }
    else if (sel == 1) { s = Wk; d = wqkv + 1048576; }
    else if (sel == 2) { s = Wv; d = wqkv + 2097152; }
    else               { s = Wo; d = wob; }
  }
  const size_t e = (size_t)off * 8;
  const float4 a = *(const float4*)(s + e);
  const float4 b = *(const float4*)(s + e + 4);
  u16x8 o;
  o[0] = f2bf(a.x); o[1] = f2bf(a.y); o[2] = f2bf(a.z); o[3] = f2bf(a.w);
  o[4] = f2bf(b.x); o[5] = f2bf(b.y); o[6] = f2bf(b.z); o[7] = f2bf(b.w);
  *(u16x8*)(d + e) = o;
}

// ---------------- merged Q + K/V projection GEMM (occ2 pipe) ----------------
__global__ __launch_bounds__(512, 4) void gemm_qkv(const u16* __restrict__ xb,
                                                   const u16* __restrict__ wqkv,
                                                   u16* __restrict__ Qd,
                                                   u16* __restrict__ KTd,
                                                   u16* __restrict__ VTd) {
  __shared__ u16 sm[32768];
  const int tid = threadIdx.x, w = tid >> 6, l = tid & 63, g = l >> 4, r = l & 15;
  const int wr = w >> 2, wc = w & 3;
  f32x4 acc[8][4] = {};
  if (blockIdx.x < 512) {
    const int wg = xcd_swz(blockIdx.x, 512);
    const int m0 = (wg & 7) * 256, n0 = (wg >> 3) * 256;
    gemm256_occ2(wqkv + 1048576, xb, m0, n0, acc, (char*)sm);
#pragma unroll
    for (int m = 0; m < 8; ++m)
#pragma unroll
      for (int n = 0; n < 4; ++n)
#pragma unroll
        for (int j = 0; j < 4; ++j) {
          const int mm = m0 + wr * 128 + m * 16 + g * 4 + j;  // (which,h,d)
          const int nn = n0 + wc * 64 + n * 16 + r;           // (b,s)
          const int which = mm >> 10, hd = mm & 1023, h = hd >> 6, d = hd & 63;
          const int b = nn >> 12, s = nn & 4095;
          u16* dst = which ? VTd : KTd;
          dst[(((size_t)(b * 16 + h)) * 64 + d) * 4096 + s] = f2bf(acc[m][n][j]);
        }
  } else {
    const int wg = xcd_swz(blockIdx.x - 512, 256);
    const int m0 = (wg >> 2) * 256, n0 = (wg & 3) * 256;
    gemm256_occ2(xb, wqkv, m0, n0, acc, (char*)sm);
#pragma unroll
    for (int m = 0; m < 8; ++m)
#pragma unroll
      for (int n = 0; n < 4; ++n)
#pragma unroll
        for (int j = 0; j < 4; ++j) {
          const int mm = m0 + wr * 128 + m * 16 + g * 4 + j;  // (b,s)
          const int nn = n0 + wc * 64 + n * 16 + r;           // (h,d)
          const int b = mm >> 12, s = mm & 4095, h = nn >> 6, d = nn & 63;
          Qd[(((size_t)(b * 16 + h)) * 4096 + s) * 64 + d] =
              f2bf(acc[m][n][j] * 0.125f);
        }
  }
}

// ---------------- final output projection (R9 pipe, control) ----------------
__global__ __launch_bounds__(512, 2) void gemm_out(const u16* __restrict__ A,
                                                   const u16* __restrict__ BT,
                                                   const float* __restrict__ bo,
                                                   float* __restrict__ out) {
  __shared__ u16 sm[65536];
  const int wg = xcd_swz(blockIdx.x, 256);
  const int m0 = (wg >> 2) * 256, n0 = (wg & 3) * 256;
  const int tid = threadIdx.x, w = tid >> 6, l = tid & 63, g = l >> 4, r = l & 15;
  const int wr = w >> 2, wc = w & 3;
  f32x4 acc[8][4] = {};
  gemm256_pipe(A, BT, m0, n0, 65536, 65536, 1024, 0, acc, (char*)sm);
#pragma unroll
  for (int m = 0; m < 8; ++m)
#pragma unroll
    for (int n = 0; n < 4; ++n)
#pragma unroll
      for (int j = 0; j < 4; ++j) {
        const int mm = m0 + wr * 128 + m * 16 + g * 4 + j;
        const int nn = n0 + wc * 64 + n * 16 + r;
        out[(size_t)mm * 1024 + nn] = acc[m][n][j] + bo[nn];
      }
}

// ---------------- E/F projections: fp32 weights direct, split-K x8 ----------
__global__ __launch_bounds__(512, 2) void gemm_small(const float* __restrict__ WeF,
                                                     const float* __restrict__ WfF,
                                                     const u16* __restrict__ KT,
                                                     const u16* __restrict__ VT,
                                                     float* __restrict__ part) {
  __shared__ u16 sm[65536];
  char* smc = (char*)sm;
  const int bx = blockIdx.x;
  const int h = bx & 15, mode = (bx >> 4) & 1, chunk = bx >> 5;
  const float* Wp = (mode == 0 ? WeF : WfF) + (size_t)h * 1048576;
  const u16* Gp = (mode == 0 ? KT : VT) + (size_t)h * 262144;
  const int tid = threadIdx.x, w = tid >> 6, l = tid & 63, g = l >> 4, r = l & 15;
  const int wr = w >> 2, wc = w & 3;
  const int xc = (tid & 7) ^ ((tid >> 3) & 7);
  const int aR = tid >> 1;
  const int aS0 = (tid & 1) * 4;

  auto stageX = [&](int kt, int buf) {
#pragma unroll
    for (int i = 0; i < 4; ++i) {
      const int row = i * 64 + (tid >> 3);
      const int b = row >> 6, d = row & 63;
      gload16(Gp + (size_t)b * 4194304 + (size_t)d * 4096 + kt * 64 + xc * 8,
              smc + buf * 65536 + i * 8192 + tid * 16);
    }
  };
  float4 aw[8];
  auto loadY = [&](int kt) {
#pragma unroll
    for (int q = 0; q < 4; ++q) {
      const float* p = Wp + (size_t)aR * 4096 + kt * 64 + (aS0 + q) * 8;
      aw[q * 2 + 0] = *(const float4*)(p);
      aw[q * 2 + 1] = *(const float4*)(p + 4);
    }
  };
  auto writeY = [&](int buf) {
#pragma unroll
    for (int q = 0; q < 4; ++q) {
      const float* f0 = (const float*)&aw[q * 2];
      const float* f1 = (const float*)&aw[q * 2 + 1];
      u16x8 o;
#pragma unroll
      for (int e = 0; e < 4; ++e) {
        o[e] = f2bf(f0[e]);
        o[e + 4] = f2bf(f1[e]);
      }
      *(u16x8*)(smc + buf * 65536 + 32768 + aR * 128 +
                (((aS0 + q) ^ (aR & 7)) << 4)) = o;
    }
  };

  f32x4 acc[8][4] = {};
  auto compute = [&](int buf) {
    const char* X = smc + buf * 65536;
    const char* Y = X + 32768;
    const char* Ar = (mode == 0) ? Y : X;
    const char* Br = (mode == 0) ? X : Y;
#pragma unroll
    for (int kk = 0; kk < 2; ++kk) {
      bf16x8 af[8], bfv[4];
#pragma unroll
      for (int n = 0; n < 4; ++n) {
        const int row = wc * 64 + n * 16 + r;
        bfv[n] = *(const bf16x8*)(Br + row * 128 + (((kk * 4 + g) ^ (r & 7)) << 4));
      }
#pragma unroll
      for (int m = 0; m < 8; ++m) {
        const int row = wr * 128 + m * 16 + r;
        af[m] = *(const bf16x8*)(Ar + row * 128 + (((kk * 4 + g) ^ (r & 7)) << 4));
      }
      __builtin_amdgcn_s_setprio(1);
#pragma unroll
      for (int m = 0; m < 8; ++m)
#pragma unroll
        for (int n = 0; n < 4; ++n)
          acc[m][n] = MFMA16(af[m], bfv[n], acc[m][n]);
      __builtin_amdgcn_s_setprio(0);
    }
  };

  const int kt0 = chunk * 8;
  stageX(kt0, 0);
  loadY(kt0);
  asm volatile("s_waitcnt vmcnt(0)" ::: "memory");
  writeY(0);
  __syncthreads();
  for (int t = 0; t < 8; ++t) {
    const int buf = t & 1;
    if (t < 7) {
      stageX(kt0 + t + 1, buf ^ 1);
      loadY(kt0 + t + 1);
    }
    compute(buf);
    if (t < 7) {
      asm volatile("s_waitcnt vmcnt(0)" ::: "memory");
      writeY(buf ^ 1);
    }
    __syncthreads();
  }

  float* Cp = part + ((size_t)((mode * 8 + chunk) * 16 + h)) * 65536;
#pragma unroll
  for (int m = 0; m < 8; ++m)
#pragma unroll
    for (int n = 0; n < 4; ++n)
#pragma unroll
      for (int j = 0; j < 4; ++j)
        Cp[(size_t)(wr * 128 + m * 16 + g * 4 + j) * 256 + wc * 64 + n * 16 + r] =
            acc[m][n][j];
}

// ---------------- reduce split-K x8 partials -> bf16 Kp / VpT ----------------
__global__ __launch_bounds__(256) void reduce_small(const float* __restrict__ part,
                                                    u16* __restrict__ Kp,
                                                    u16* __restrict__ VpT) {
  const int i = blockIdx.x * 256 + threadIdx.x;
  const int mode = i >> 18;
  const int rem = i & 262143;
  const int h = rem >> 14;
  const int e = (rem & 16383) * 4;
  const int m = e >> 8, n = e & 255;
  const float* pb = part + ((size_t)mode * 128 + h) * 65536 + e;
  float4 acc = *(const float4*)(pb);
#pragma unroll
  for (int c = 1; c < 8; ++c) {
    const float4 s = *(const float4*)(pb + (size_t)c * 1048576);
    acc.x += s.x; acc.y += s.y; acc.z += s.z; acc.w += s.w;
  }
  ushort4 o;
  o.x = f2bf(acc.x); o.y = f2bf(acc.y); o.z = f2bf(acc.z); o.w = f2bf(acc.w);
  if (mode == 0) {
    const int b = n >> 6, d = n & 63;
    *(ushort4*)(Kp + ((size_t)(b * 16 + h)) * 16384 + m * 64 + d) = o;
  } else {
    const int b = m >> 6, d = m & 63;
    *(ushort4*)(VpT + ((size_t)(b * 16 + h)) * 16384 + d * 256 + n) = o;
  }
}

// ---------------- fused scores + softmax + PV ----------------
__global__ __launch_bounds__(256, 1) void attn_fused(const u16* __restrict__ Q,
                                                     const u16* __restrict__ Kp,
                                                     const u16* __restrict__ VpT,
                                                     u16* __restrict__ att) {
  __shared__ u16 P[4][16 * 264];
  const int gid = blockIdx.x;
  const int bh = gid >> 3;
  const int st = gid & 7;
  const int hh = bh & 15, b = bh >> 4;
  const int tid = threadIdx.x, w = tid >> 6, l = tid & 63, g = l >> 4, r = l & 15;
  const u16* Kpb = Kp + (size_t)bh * 256 * 64;
  const u16* Vb = VpT + (size_t)bh * 64 * 256;

  bf16x8 kf[32];
  bf16x8 vf[32];
#pragma unroll
  for (int fn = 0; fn < 16; ++fn) {
    kf[fn * 2 + 0] = ldf(Kpb + (fn * 16 + r) * 64 + g * 8);
    kf[fn * 2 + 1] = ldf(Kpb + (fn * 16 + r) * 64 + 32 + g * 8);
  }
#pragma unroll
  for (int fn2 = 0; fn2 < 4; ++fn2)
#pragma unroll
    for (int kk = 0; kk < 8; ++kk)
      vf[fn2 * 8 + kk] = ldf(Vb + (fn2 * 16 + r) * 256 + kk * 32 + g * 8);

  u16* Pw = P[w];
  for (int t = 0; t < 8; ++t) {
    const int s0 = st * 512 + t * 64 + w * 16;
    const u16* Qb = Q + ((size_t)bh * 4096 + s0) * 64;
    const bf16x8 qf0 = ldf(Qb + r * 64 + g * 8);
    const bf16x8 qf1 = ldf(Qb + r * 64 + 32 + g * 8);
    f32x4 sc[16];
#pragma unroll
    for (int fn = 0; fn < 16; ++fn) {
      sc[fn] = MFMA16(qf0, kf[fn * 2 + 0], (f32x4){});
      sc[fn] = MFMA16(qf1, kf[fn * 2 + 1], sc[fn]);
    }
    float rinv[4];
#pragma unroll
    for (int j = 0; j < 4; ++j) {
      float sum = 0.f;
#pragma unroll
      for (int fn = 0; fn < 16; ++fn) {
        const float e = __expf(sc[fn][j]);
        sc[fn][j] = e;
        sum += e;
      }
      sum += __shfl_xor(sum, 1);
      sum += __shfl_xor(sum, 2);
      sum += __shfl_xor(sum, 4);
      sum += __shfl_xor(sum, 8);
      rinv[j] = 1.0f / sum;
    }
#pragma unroll
    for (int fn = 0; fn < 16; ++fn)
#pragma unroll
      for (int j = 0; j < 4; ++j)
        Pw[(g * 4 + j) * 264 + fn * 16 + r] = f2bf(sc[fn][j]);

    f32x4 o[4] = {};
#pragma unroll
    for (int kk = 0; kk < 8; ++kk) {
      const bf16x8 pa = ldf(Pw + r * 264 + kk * 32 + g * 8);
#pragma unroll
      for (int fn2 = 0; fn2 < 4; ++fn2)
        o[fn2] = MFMA16(pa, vf[fn2 * 8 + kk], o[fn2]);
    }
#pragma unroll
    for (int fn2 = 0; fn2 < 4; ++fn2)
#pragma unroll
      for (int j = 0; j < 4; ++j) {
        const int s = s0 + g * 4 + j;
        const int d = fn2 * 16 + r;
        att[((size_t)b * 4096 + s) * 1024 + hh * 64 + d] = f2bf(o[fn2][j] * rinv[j]);
      }
  }
}

extern "C" void kernel_launch(void* const* d_in, const int* in_sizes, int n_in,
                              void* d_out, int out_size, void* d_ws, size_t ws_size,
                              hipStream_t stream) {
  (void)in_sizes; (void)n_in; (void)out_size; (void)ws_size;
  const float* x  = (const float*)d_in[0];
  const float* Wq = (const float*)d_in[1];
  const float* Wk = (const float*)d_in[2];
  const float* Wv = (const float*)d_in[3];
  const float* We = (const float*)d_in[4];
  const float* Wf = (const float*)d_in[5];
  const float* Wo = (const float*)d_in[6];
  const float* bo = (const float*)d_in[7];
  char* ws = (char*)d_ws;
  u16* xb    = (u16*)(ws + 0);           // x bf16 [16384][1024]
  float* prt = (float*)(ws + 0);         // split-K x8 partials (67,108,864 B)
  u16* wqkv  = (u16*)(ws + 33554432);    // Wq|Wk|Wv [3072][1024]
  u16* att   = (u16*)(ws + 73400320);    // attn output [16384][1024] bf16
  u16* wob   = (u16*)(ws + 106954752);   // Wo [1024][1024]
  u16* Qd    = (u16*)(ws + 109051904);   // Q/8 [64][4096][64]
  u16* KTd   = (u16*)(ws + 142606336);   // K^T [64][64][4096]
  u16* VTd   = (u16*)(ws + 176160768);   // V^T [64][64][4096]
  u16* Kpd   = (u16*)(ws + 209715200);   // Kp_t [64][256][64]
  u16* VpTd  = (u16*)(ws + 211812352);   // VpT  [64][64][256]

  cvt_all<<<10240, 256, 0, stream>>>(x, Wq, Wk, Wv, Wo, xb, wqkv, wob);
  gemm_qkv<<<768, 512, 0, stream>>>(xb, wqkv, Qd, KTd, VTd);
  gemm_small<<<256, 512, 0, stream>>>(We, Wf, KTd, VTd, prt);
  reduce_small<<<2048, 256, 0, stream>>>(prt, Kpd, VpTd);
  attn_fused<<<512, 256, 0, stream>>>(Qd, Kpd, VpTd, att);
  gemm_out<<<256, 512, 0, stream>>>(att, wob, bo, (float*)d_out);
}

// Round 17
// 307.470 us; speedup vs baseline: 4.3891x; 4.3891x over previous
//
#include <hip/hip_runtime.h>
#include <stdint.h>

// Linformer CMHAttention on MI355X (gfx950).
// B=4,S=4096,C=1024,H=16,D=64,K=256. bf16 MFMA 16x16x32, fp32 accum.
// R17: R16 occupancy experiment, corrected. R16's __launch_bounds__(512,4)
//      capped VGPRs at 64 -> acc spilled to scratch (WRITE 3GB, 1349 µs).
//      Same occ2 pipe (BK32, 64KB LDS -> 2 blocks/CU) with (512,2): VGPR ~100,
//      no spill; TLP comes from the second co-resident block. gemm_out stays
//      on R9 pipe (control). Rest byte-identical R15.

typedef unsigned short u16;
typedef __bf16 bf16t;
typedef bf16t bf16x8 __attribute__((ext_vector_type(8)));
typedef float f32x4 __attribute__((ext_vector_type(4)));
typedef u16 u16x8 __attribute__((ext_vector_type(8)));

#define MFMA16(a, b, c) __builtin_amdgcn_mfma_f32_16x16x32_bf16((a), (b), (c), 0, 0, 0)

__device__ __forceinline__ u16 f2bf(float f) {
  return __builtin_bit_cast(u16, (bf16t)f);
}

__device__ __forceinline__ bf16x8 ldf(const u16* p) { return *(const bf16x8*)p; }

__device__ __forceinline__ void gload16(const void* g, void* l) {
  __builtin_amdgcn_global_load_lds(
      (__attribute__((address_space(1))) void*)g,
      (__attribute__((address_space(3))) void*)l, 16, 0, 0);
}

__device__ __forceinline__ int xcd_swz(int orig, int nwg) {
  return (orig & 7) * (nwg >> 3) + (orig >> 3);
}

#define FENCE asm volatile("" ::: "memory")
#define BAR                                  \
  do {                                       \
    FENCE;                                   \
    __builtin_amdgcn_s_barrier();            \
    FENCE;                                   \
  } while (0)

// ========== R16/17 pipe: 256x256, BK32, 64KB LDS (2 blocks/CU) ==========
__device__ __forceinline__ void gemm256_occ2(const u16* __restrict__ A,
                                             const u16* __restrict__ B,
                                             int m0, int n0, f32x4 acc[8][4],
                                             char* smc) {
  const int tid = threadIdx.x;
  const int w = tid >> 6, l = tid & 63, g = l >> 4, r = l & 15;
  const int wr = w >> 2, wc = w & 3;
  const int gx = ((g ^ ((r >> 1) & 3)) << 4);  // read-side swizzle (bytes)

  auto stageAB = [&](int T, int buf) {
#pragma unroll
    for (int i = 0; i < 2; ++i) {
      const int G = i * 512 + tid;  // 0..1023
      const int row = G >> 2, slot = G & 3;
      const int sc = slot ^ ((row >> 1) & 3);  // pre-swizzled source chunk
      gload16((const char*)A + ((size_t)(m0 + row) * 1024 + T * 32) * 2 + sc * 16,
              smc + buf * 32768 + G * 16);
      gload16((const char*)B + ((size_t)(n0 + row) * 1024 + T * 32) * 2 + sc * 16,
              smc + buf * 32768 + 16384 + G * 16);
    }
  };

  stageAB(0, 0);
#pragma unroll 1
  for (int t = 0; t < 32; ++t) {
    const int buf = t & 1;
    stageAB(t < 31 ? t + 1 : 31, buf ^ 1);
    asm volatile("s_waitcnt vmcnt(4)" ::: "memory");  // tile t landed
    BAR;
    const char* At = smc + buf * 32768;
    const char* Bt = At + 16384;
    bf16x8 af[8], bfv[4];
#pragma unroll
    for (int n = 0; n < 4; ++n)
      bfv[n] = *(const bf16x8*)(Bt + (wc * 64 + n * 16 + r) * 64 + gx);
#pragma unroll
    for (int m = 0; m < 8; ++m)
      af[m] = *(const bf16x8*)(At + (wr * 128 + m * 16 + r) * 64 + gx);
    __builtin_amdgcn_s_setprio(1);
#pragma unroll
    for (int m = 0; m < 8; ++m)
#pragma unroll
      for (int n = 0; n < 4; ++n)
        acc[m][n] = MFMA16(af[m], bfv[n], acc[m][n]);
    __builtin_amdgcn_s_setprio(0);
    BAR;
  }
}

// ========== R9 pipe (proven, 7-half-tile prologue) — control ==========
__device__ __forceinline__ void gemm256_pipe(const u16* __restrict__ A,
                                             const u16* __restrict__ B,
                                             int m0, int n0, int sA1, int sB1,
                                             int s0, int kt0, f32x4 acc[8][4],
                                             char* smc) {
  const int tid = threadIdx.x;
  const int w = tid >> 6, l = tid & 63, g = l >> 4, r = l & 15;
  const int wr = w >> 2, wc = w & 3;
  const int lrow = l >> 2;
  const int ksw = (((l & 3) ^ ((l >> 3) & 3)) << 4);
  const int gx = ((g ^ ((r >> 1) & 3)) << 4);

  auto stage = [&](const u16* Base, int r0, int s1, int T, int ch, int ldsoff) {
#pragma unroll
    for (int i = 0; i < 2; ++i) {
      const int row = r0 + (w * 2 + i) * 16 + lrow;
      const size_t eoff = (size_t)(row >> 6) * s1 + (size_t)(row & 63) * s0;
      gload16((const char*)Base + eoff * 2 + ((kt0 + T) * 64 + ch * 32) * 2 + ksw,
              smc + ldsoff + (w * 2 + i) * 1024);
    }
  };

#define RD_B(dst, Bt)                                                     \
  _Pragma("unroll") for (int n = 0; n < 4; ++n)                           \
      dst[n] = *(const bf16x8*)((Bt) + (wc * 64 + n * 16 + r) * 64 + gx);
#define RD_A(dst, At, MH)                                                 \
  _Pragma("unroll") for (int m = 0; m < 4; ++m)                           \
      dst[m] = *(const bf16x8*)((At) + (wr * 128 + (MH)*64 + m * 16 + r) * 64 + gx);
#define QUAD(MH)                                                          \
  __builtin_amdgcn_s_setprio(1);                                          \
  _Pragma("unroll") for (int m = 0; m < 4; ++m)                           \
      _Pragma("unroll") for (int n = 0; n < 4; ++n)                       \
          acc[(MH)*4 + m][n] = MFMA16(af[m], bfv[n], acc[(MH)*4 + m][n]); \
  __builtin_amdgcn_s_setprio(0);

  stage(B, n0, sB1, 0, 0, 0 + 32768);      // B0(0)
  stage(A, m0, sA1, 0, 0, 0 + 0);          // A0(0)
  stage(B, n0, sB1, 0, 1, 0 + 49152);      // B1(0)
  stage(A, m0, sA1, 0, 1, 0 + 16384);      // A1(0)
  stage(B, n0, sB1, 1, 0, 65536 + 32768);  // B0(1)
  stage(A, m0, sA1, 1, 0, 65536 + 0);      // A0(1)
  stage(B, n0, sB1, 1, 1, 65536 + 49152);  // B1(1)
  asm volatile("s_waitcnt vmcnt(10)" ::: "memory");
  BAR;

  for (int t = 0; t < 16; ++t) {
    const int buf = (t & 1) << 16, nb = buf ^ 65536;
    const int T1 = t < 15 ? t + 1 : 15;
    const int T2 = t < 14 ? t + 2 : 15;
    bf16x8 af[4], bfv[4];
    const char* At0 = smc + buf;
    const char* At1 = smc + buf + 16384;
    const char* Bt0 = smc + buf + 32768;
    const char* Bt1 = smc + buf + 49152;

    RD_B(bfv, Bt0)
    RD_A(af, At0, 0)
    stage(A, m0, sA1, T1, 1, nb + 16384);
    BAR;
    QUAD(0)
    BAR;
    RD_A(af, At0, 1)
    stage(B, n0, sB1, T2, 0, buf + 32768);
    asm volatile("s_waitcnt vmcnt(10)" ::: "memory");
    BAR;
    QUAD(1)
    BAR;
    RD_B(bfv, Bt1)
    RD_A(af, At1, 0)
    stage(A, m0, sA1, T2, 0, buf + 0);
    BAR;
    QUAD(0)
    BAR;
    RD_A(af, At1, 1)
    stage(B, n0, sB1, T2, 1, buf + 49152);
    asm volatile("s_waitcnt vmcnt(10)" ::: "memory");
    BAR;
    QUAD(1)
    BAR;
  }
#undef RD_B
#undef RD_A
#undef QUAD
}

// ---------------- f32 -> bf16 conversion: x + small weights only ------------
__global__ __launch_bounds__(256) void cvt_all(
    const float* __restrict__ x, const float* __restrict__ Wq,
    const float* __restrict__ Wk, const float* __restrict__ Wv,
    const float* __restrict__ Wo, u16* __restrict__ xb, u16* __restrict__ wqkv,
    u16* __restrict__ wob) {
  const int i = blockIdx.x * 256 + threadIdx.x;
  const float* s;
  u16* d;
  int off;
  if (i < 2097152) {
    s = x; d = xb; off = i;
  } else {
    const int j = i - 2097152, sel = j >> 17;
    off = j & 131071;
    if (sel == 0)      { s = Wq; d = wqkv; }
    else if (sel == 1) { s = Wk; d = wqkv + 1048576; }
    else if (sel == 2) { s = Wv; d = wqkv + 2097152; }
    else               { s = Wo; d = wob; }
  }
  const size_t e = (size_t)off * 8;
  const float4 a = *(const float4*)(s + e);
  const float4 b = *(const float4*)(s + e + 4);
  u16x8 o;
  o[0] = f2bf(a.x); o[1] = f2bf(a.y); o[2] = f2bf(a.z); o[3] = f2bf(a.w);
  o[4] = f2bf(b.x); o[5] = f2bf(b.y); o[6] = f2bf(b.z); o[7] = f2bf(b.w);
  *(u16x8*)(d + e) = o;
}

// ---------------- merged Q + K/V projection GEMM (occ2 pipe) ----------------
__global__ __launch_bounds__(512, 2) void gemm_qkv(const u16* __restrict__ xb,
                                                   const u16* __restrict__ wqkv,
                                                   u16* __restrict__ Qd,
                                                   u16* __restrict__ KTd,
                                                   u16* __restrict__ VTd) {
  __shared__ u16 sm[32768];
  const int tid = threadIdx.x, w = tid >> 6, l = tid & 63, g = l >> 4, r = l & 15;
  const int wr = w >> 2, wc = w & 3;
  f32x4 acc[8][4] = {};
  if (blockIdx.x < 512) {
    const int wg = xcd_swz(blockIdx.x, 512);
    const int m0 = (wg & 7) * 256, n0 = (wg >> 3) * 256;
    gemm256_occ2(wqkv + 1048576, xb, m0, n0, acc, (char*)sm);
#pragma unroll
    for (int m = 0; m < 8; ++m)
#pragma unroll
      for (int n = 0; n < 4; ++n)
#pragma unroll
        for (int j = 0; j < 4; ++j) {
          const int mm = m0 + wr * 128 + m * 16 + g * 4 + j;  // (which,h,d)
          const int nn = n0 + wc * 64 + n * 16 + r;           // (b,s)
          const int which = mm >> 10, hd = mm & 1023, h = hd >> 6, d = hd & 63;
          const int b = nn >> 12, s = nn & 4095;
          u16* dst = which ? VTd : KTd;
          dst[(((size_t)(b * 16 + h)) * 64 + d) * 4096 + s] = f2bf(acc[m][n][j]);
        }
  } else {
    const int wg = xcd_swz(blockIdx.x - 512, 256);
    const int m0 = (wg >> 2) * 256, n0 = (wg & 3) * 256;
    gemm256_occ2(xb, wqkv, m0, n0, acc, (char*)sm);
#pragma unroll
    for (int m = 0; m < 8; ++m)
#pragma unroll
      for (int n = 0; n < 4; ++n)
#pragma unroll
        for (int j = 0; j < 4; ++j) {
          const int mm = m0 + wr * 128 + m * 16 + g * 4 + j;  // (b,s)
          const int nn = n0 + wc * 64 + n * 16 + r;           // (h,d)
          const int b = mm >> 12, s = mm & 4095, h = nn >> 6, d = nn & 63;
          Qd[(((size_t)(b * 16 + h)) * 4096 + s) * 64 + d] =
              f2bf(acc[m][n][j] * 0.125f);
        }
  }
}

// ---------------- final output projection (R9 pipe, control) ----------------
__global__ __launch_bounds__(512, 2) void gemm_out(const u16* __restrict__ A,
                                                   const u16* __restrict__ BT,
                                                   const float* __restrict__ bo,
                                                   float* __restrict__ out) {
  __shared__ u16 sm[65536];
  const int wg = xcd_swz(blockIdx.x, 256);
  const int m0 = (wg >> 2) * 256, n0 = (wg & 3) * 256;
  const int tid = threadIdx.x, w = tid >> 6, l = tid & 63, g = l >> 4, r = l & 15;
  const int wr = w >> 2, wc = w & 3;
  f32x4 acc[8][4] = {};
  gemm256_pipe(A, BT, m0, n0, 65536, 65536, 1024, 0, acc, (char*)sm);
#pragma unroll
  for (int m = 0; m < 8; ++m)
#pragma unroll
    for (int n = 0; n < 4; ++n)
#pragma unroll
      for (int j = 0; j < 4; ++j) {
        const int mm = m0 + wr * 128 + m * 16 + g * 4 + j;
        const int nn = n0 + wc * 64 + n * 16 + r;
        out[(size_t)mm * 1024 + nn] = acc[m][n][j] + bo[nn];
      }
}

// ---------------- E/F projections: fp32 weights direct, split-K x8 ----------
__global__ __launch_bounds__(512, 2) void gemm_small(const float* __restrict__ WeF,
                                                     const float* __restrict__ WfF,
                                                     const u16* __restrict__ KT,
                                                     const u16* __restrict__ VT,
                                                     float* __restrict__ part) {
  __shared__ u16 sm[65536];
  char* smc = (char*)sm;
  const int bx = blockIdx.x;
  const int h = bx & 15, mode = (bx >> 4) & 1, chunk = bx >> 5;
  const float* Wp = (mode == 0 ? WeF : WfF) + (size_t)h * 1048576;
  const u16* Gp = (mode == 0 ? KT : VT) + (size_t)h * 262144;
  const int tid = threadIdx.x, w = tid >> 6, l = tid & 63, g = l >> 4, r = l & 15;
  const int wr = w >> 2, wc = w & 3;
  const int xc = (tid & 7) ^ ((tid >> 3) & 7);
  const int aR = tid >> 1;
  const int aS0 = (tid & 1) * 4;

  auto stageX = [&](int kt, int buf) {
#pragma unroll
    for (int i = 0; i < 4; ++i) {
      const int row = i * 64 + (tid >> 3);
      const int b = row >> 6, d = row & 63;
      gload16(Gp + (size_t)b * 4194304 + (size_t)d * 4096 + kt * 64 + xc * 8,
              smc + buf * 65536 + i * 8192 + tid * 16);
    }
  };
  float4 aw[8];
  auto loadY = [&](int kt) {
#pragma unroll
    for (int q = 0; q < 4; ++q) {
      const float* p = Wp + (size_t)aR * 4096 + kt * 64 + (aS0 + q) * 8;
      aw[q * 2 + 0] = *(const float4*)(p);
      aw[q * 2 + 1] = *(const float4*)(p + 4);
    }
  };
  auto writeY = [&](int buf) {
#pragma unroll
    for (int q = 0; q < 4; ++q) {
      const float* f0 = (const float*)&aw[q * 2];
      const float* f1 = (const float*)&aw[q * 2 + 1];
      u16x8 o;
#pragma unroll
      for (int e = 0; e < 4; ++e) {
        o[e] = f2bf(f0[e]);
        o[e + 4] = f2bf(f1[e]);
      }
      *(u16x8*)(smc + buf * 65536 + 32768 + aR * 128 +
                (((aS0 + q) ^ (aR & 7)) << 4)) = o;
    }
  };

  f32x4 acc[8][4] = {};
  auto compute = [&](int buf) {
    const char* X = smc + buf * 65536;
    const char* Y = X + 32768;
    const char* Ar = (mode == 0) ? Y : X;
    const char* Br = (mode == 0) ? X : Y;
#pragma unroll
    for (int kk = 0; kk < 2; ++kk) {
      bf16x8 af[8], bfv[4];
#pragma unroll
      for (int n = 0; n < 4; ++n) {
        const int row = wc * 64 + n * 16 + r;
        bfv[n] = *(const bf16x8*)(Br + row * 128 + (((kk * 4 + g) ^ (r & 7)) << 4));
      }
#pragma unroll
      for (int m = 0; m < 8; ++m) {
        const int row = wr * 128 + m * 16 + r;
        af[m] = *(const bf16x8*)(Ar + row * 128 + (((kk * 4 + g) ^ (r & 7)) << 4));
      }
      __builtin_amdgcn_s_setprio(1);
#pragma unroll
      for (int m = 0; m < 8; ++m)
#pragma unroll
        for (int n = 0; n < 4; ++n)
          acc[m][n] = MFMA16(af[m], bfv[n], acc[m][n]);
      __builtin_amdgcn_s_setprio(0);
    }
  };

  const int kt0 = chunk * 8;
  stageX(kt0, 0);
  loadY(kt0);
  asm volatile("s_waitcnt vmcnt(0)" ::: "memory");
  writeY(0);
  __syncthreads();
  for (int t = 0; t < 8; ++t) {
    const int buf = t & 1;
    if (t < 7) {
      stageX(kt0 + t + 1, buf ^ 1);
      loadY(kt0 + t + 1);
    }
    compute(buf);
    if (t < 7) {
      asm volatile("s_waitcnt vmcnt(0)" ::: "memory");
      writeY(buf ^ 1);
    }
    __syncthreads();
  }

  float* Cp = part + ((size_t)((mode * 8 + chunk) * 16 + h)) * 65536;
#pragma unroll
  for (int m = 0; m < 8; ++m)
#pragma unroll
    for (int n = 0; n < 4; ++n)
#pragma unroll
      for (int j = 0; j < 4; ++j)
        Cp[(size_t)(wr * 128 + m * 16 + g * 4 + j) * 256 + wc * 64 + n * 16 + r] =
            acc[m][n][j];
}

// ---------------- reduce split-K x8 partials -> bf16 Kp / VpT ----------------
__global__ __launch_bounds__(256) void reduce_small(const float* __restrict__ part,
                                                    u16* __restrict__ Kp,
                                                    u16* __restrict__ VpT) {
  const int i = blockIdx.x * 256 + threadIdx.x;
  const int mode = i >> 18;
  const int rem = i & 262143;
  const int h = rem >> 14;
  const int e = (rem & 16383) * 4;
  const int m = e >> 8, n = e & 255;
  const float* pb = part + ((size_t)mode * 128 + h) * 65536 + e;
  float4 acc = *(const float4*)(pb);
#pragma unroll
  for (int c = 1; c < 8; ++c) {
    const float4 s = *(const float4*)(pb + (size_t)c * 1048576);
    acc.x += s.x; acc.y += s.y; acc.z += s.z; acc.w += s.w;
  }
  ushort4 o;
  o.x = f2bf(acc.x); o.y = f2bf(acc.y); o.z = f2bf(acc.z); o.w = f2bf(acc.w);
  if (mode == 0) {
    const int b = n >> 6, d = n & 63;
    *(ushort4*)(Kp + ((size_t)(b * 16 + h)) * 16384 + m * 64 + d) = o;
  } else {
    const int b = m >> 6, d = m & 63;
    *(ushort4*)(VpT + ((size_t)(b * 16 + h)) * 16384 + d * 256 + n) = o;
  }
}

// ---------------- fused scores + softmax + PV ----------------
__global__ __launch_bounds__(256, 1) void attn_fused(const u16* __restrict__ Q,
                                                     const u16* __restrict__ Kp,
                                                     const u16* __restrict__ VpT,
                                                     u16* __restrict__ att) {
  __shared__ u16 P[4][16 * 264];
  const int gid = blockIdx.x;
  const int bh = gid >> 3;
  const int st = gid & 7;
  const int hh = bh & 15, b = bh >> 4;
  const int tid = threadIdx.x, w = tid >> 6, l = tid & 63, g = l >> 4, r = l & 15;
  const u16* Kpb = Kp + (size_t)bh * 256 * 64;
  const u16* Vb = VpT + (size_t)bh * 64 * 256;

  bf16x8 kf[32];
  bf16x8 vf[32];
#pragma unroll
  for (int fn = 0; fn < 16; ++fn) {
    kf[fn * 2 + 0] = ldf(Kpb + (fn * 16 + r) * 64 + g * 8);
    kf[fn * 2 + 1] = ldf(Kpb + (fn * 16 + r) * 64 + 32 + g * 8);
  }
#pragma unroll
  for (int fn2 = 0; fn2 < 4; ++fn2)
#pragma unroll
    for (int kk = 0; kk < 8; ++kk)
      vf[fn2 * 8 + kk] = ldf(Vb + (fn2 * 16 + r) * 256 + kk * 32 + g * 8);

  u16* Pw = P[w];
  for (int t = 0; t < 8; ++t) {
    const int s0 = st * 512 + t * 64 + w * 16;
    const u16* Qb = Q + ((size_t)bh * 4096 + s0) * 64;
    const bf16x8 qf0 = ldf(Qb + r * 64 + g * 8);
    const bf16x8 qf1 = ldf(Qb + r * 64 + 32 + g * 8);
    f32x4 sc[16];
#pragma unroll
    for (int fn = 0; fn < 16; ++fn) {
      sc[fn] = MFMA16(qf0, kf[fn * 2 + 0], (f32x4){});
      sc[fn] = MFMA16(qf1, kf[fn * 2 + 1], sc[fn]);
    }
    float rinv[4];
#pragma unroll
    for (int j = 0; j < 4; ++j) {
      float sum = 0.f;
#pragma unroll
      for (int fn = 0; fn < 16; ++fn) {
        const float e = __expf(sc[fn][j]);
        sc[fn][j] = e;
        sum += e;
      }
      sum += __shfl_xor(sum, 1);
      sum += __shfl_xor(sum, 2);
      sum += __shfl_xor(sum, 4);
      sum += __shfl_xor(sum, 8);
      rinv[j] = 1.0f / sum;
    }
#pragma unroll
    for (int fn = 0; fn < 16; ++fn)
#pragma unroll
      for (int j = 0; j < 4; ++j)
        Pw[(g * 4 + j) * 264 + fn * 16 + r] = f2bf(sc[fn][j]);

    f32x4 o[4] = {};
#pragma unroll
    for (int kk = 0; kk < 8; ++kk) {
      const bf16x8 pa = ldf(Pw + r * 264 + kk * 32 + g * 8);
#pragma unroll
      for (int fn2 = 0; fn2 < 4; ++fn2)
        o[fn2] = MFMA16(pa, vf[fn2 * 8 + kk], o[fn2]);
    }
#pragma unroll
    for (int fn2 = 0; fn2 < 4; ++fn2)
#pragma unroll
      for (int j = 0; j < 4; ++j) {
        const int s = s0 + g * 4 + j;
        const int d = fn2 * 16 + r;
        att[((size_t)b * 4096 + s) * 1024 + hh * 64 + d] = f2bf(o[fn2][j] * rinv[j]);
      }
  }
}

extern "C" void kernel_launch(void* const* d_in, const int* in_sizes, int n_in,
                              void* d_out, int out_size, void* d_ws, size_t ws_size,
                              hipStream_t stream) {
  (void)in_sizes; (void)n_in; (void)out_size; (void)ws_size;
  const float* x  = (const float*)d_in[0];
  const float* Wq = (const float*)d_in[1];
  const float* Wk = (const float*)d_in[2];
  const float* Wv = (const float*)d_in[3];
  const float* We = (const float*)d_in[4];
  const float* Wf = (const float*)d_in[5];
  const float* Wo = (const float*)d_in[6];
  const float* bo = (const float*)d_in[7];
  char* ws = (char*)d_ws;
  u16* xb    = (u16*)(ws + 0);           // x bf16 [16384][1024]
  float* prt = (float*)(ws + 0);         // split-K x8 partials (67,108,864 B)
  u16* wqkv  = (u16*)(ws + 33554432);    // Wq|Wk|Wv [3072][1024]
  u16* att   = (u16*)(ws + 73400320);    // attn output [16384][1024] bf16
  u16* wob   = (u16*)(ws + 106954752);   // Wo [1024][1024]
  u16* Qd    = (u16*)(ws + 109051904);   // Q/8 [64][4096][64]
  u16* KTd   = (u16*)(ws + 142606336);   // K^T [64][64][4096]
  u16* VTd   = (u16*)(ws + 176160768);   // V^T [64][64][4096]
  u16* Kpd   = (u16*)(ws + 209715200);   // Kp_t [64][256][64]
  u16* VpTd  = (u16*)(ws + 211812352);   // VpT  [64][64][256]

  cvt_all<<<10240, 256, 0, stream>>>(x, Wq, Wk, Wv, Wo, xb, wqkv, wob);
  gemm_qkv<<<768, 512, 0, stream>>>(xb, wqkv, Qd, KTd, VTd);
  gemm_small<<<256, 512, 0, stream>>>(We, Wf, KTd, VTd, prt);
  reduce_small<<<2048, 256, 0, stream>>>(prt, Kpd, VpTd);
  attn_fused<<<512, 256, 0, stream>>>(Qd, Kpd, VpTd, att);
  gemm_out<<<256, 512, 0, stream>>>(att, wob, bo, (float*)d_out);
}

// Round 18
// 305.164 us; speedup vs baseline: 4.4222x; 1.0076x over previous
//
#include <hip/hip_runtime.h>
#include <stdint.h>

// Linformer CMHAttention on MI355X (gfx950).
// B=4,S=4096,C=1024,H=16,D=64,K=256. bf16 MFMA 16x16x32, fp32 accum.
// R18: best-known configuration (== R15/R13, 307.7-308.0 µs measured).
//      gemm_qkv back on the R9 pipe (112 µs vs occ2's 116; R17's occupancy
//      experiment was null: 2 blocks/CU -> MfmaUtil 39 vs 41, occ 21 vs 20).
//      Seven schedule/occupancy levers tested on the ~40% MfmaUtil plateau
//      (R7 swizzle, R8 8-barrier, R9 deep prefetch, R10 BK32 ring, R14 B-reg,
//      R16/17 occupancy) — all null/negative; plateau is structural at this
//      source level. All other kernels sit within ~15% of HBM floors.

typedef unsigned short u16;
typedef __bf16 bf16t;
typedef bf16t bf16x8 __attribute__((ext_vector_type(8)));
typedef float f32x4 __attribute__((ext_vector_type(4)));
typedef u16 u16x8 __attribute__((ext_vector_type(8)));

#define MFMA16(a, b, c) __builtin_amdgcn_mfma_f32_16x16x32_bf16((a), (b), (c), 0, 0, 0)

__device__ __forceinline__ u16 f2bf(float f) {
  return __builtin_bit_cast(u16, (bf16t)f);
}

__device__ __forceinline__ bf16x8 ldf(const u16* p) { return *(const bf16x8*)p; }

__device__ __forceinline__ void gload16(const void* g, void* l) {
  __builtin_amdgcn_global_load_lds(
      (__attribute__((address_space(1))) void*)g,
      (__attribute__((address_space(3))) void*)l, 16, 0, 0);
}

__device__ __forceinline__ int xcd_swz(int orig, int nwg) {
  return (orig & 7) * (nwg >> 3) + (orig >> 3);
}

#define FENCE asm volatile("" ::: "memory")
#define BAR                                  \
  do {                                       \
    FENCE;                                   \
    __builtin_amdgcn_s_barrier();            \
    FENCE;                                   \
  } while (0)

// ========== R9 pipe (proven, 7-half-tile prologue) ==========
__device__ __forceinline__ void gemm256_pipe(const u16* __restrict__ A,
                                             const u16* __restrict__ B,
                                             int m0, int n0, int sA1, int sB1,
                                             int s0, int kt0, f32x4 acc[8][4],
                                             char* smc) {
  const int tid = threadIdx.x;
  const int w = tid >> 6, l = tid & 63, g = l >> 4, r = l & 15;
  const int wr = w >> 2, wc = w & 3;
  const int lrow = l >> 2;
  const int ksw = (((l & 3) ^ ((l >> 3) & 3)) << 4);
  const int gx = ((g ^ ((r >> 1) & 3)) << 4);

  auto stage = [&](const u16* Base, int r0, int s1, int T, int ch, int ldsoff) {
#pragma unroll
    for (int i = 0; i < 2; ++i) {
      const int row = r0 + (w * 2 + i) * 16 + lrow;
      const size_t eoff = (size_t)(row >> 6) * s1 + (size_t)(row & 63) * s0;
      gload16((const char*)Base + eoff * 2 + ((kt0 + T) * 64 + ch * 32) * 2 + ksw,
              smc + ldsoff + (w * 2 + i) * 1024);
    }
  };

#define RD_B(dst, Bt)                                                     \
  _Pragma("unroll") for (int n = 0; n < 4; ++n)                           \
      dst[n] = *(const bf16x8*)((Bt) + (wc * 64 + n * 16 + r) * 64 + gx);
#define RD_A(dst, At, MH)                                                 \
  _Pragma("unroll") for (int m = 0; m < 4; ++m)                           \
      dst[m] = *(const bf16x8*)((At) + (wr * 128 + (MH)*64 + m * 16 + r) * 64 + gx);
#define QUAD(MH)                                                          \
  __builtin_amdgcn_s_setprio(1);                                          \
  _Pragma("unroll") for (int m = 0; m < 4; ++m)                           \
      _Pragma("unroll") for (int n = 0; n < 4; ++n)                       \
          acc[(MH)*4 + m][n] = MFMA16(af[m], bfv[n], acc[(MH)*4 + m][n]); \
  __builtin_amdgcn_s_setprio(0);

  // prologue: 7 half-tiles, oldest-first matching steady-state issue order
  stage(B, n0, sB1, 0, 0, 0 + 32768);      // B0(0)
  stage(A, m0, sA1, 0, 0, 0 + 0);          // A0(0)
  stage(B, n0, sB1, 0, 1, 0 + 49152);      // B1(0)
  stage(A, m0, sA1, 0, 1, 0 + 16384);      // A1(0)
  stage(B, n0, sB1, 1, 0, 65536 + 32768);  // B0(1)
  stage(A, m0, sA1, 1, 0, 65536 + 0);      // A0(1)
  stage(B, n0, sB1, 1, 1, 65536 + 49152);  // B1(1)
  asm volatile("s_waitcnt vmcnt(10)" ::: "memory");
  BAR;

  for (int t = 0; t < 16; ++t) {
    const int buf = (t & 1) << 16, nb = buf ^ 65536;
    const int T1 = t < 15 ? t + 1 : 15;
    const int T2 = t < 14 ? t + 2 : 15;
    bf16x8 af[4], bfv[4];
    const char* At0 = smc + buf;
    const char* At1 = smc + buf + 16384;
    const char* Bt0 = smc + buf + 32768;
    const char* Bt1 = smc + buf + 49152;

    RD_B(bfv, Bt0)
    RD_A(af, At0, 0)
    stage(A, m0, sA1, T1, 1, nb + 16384);
    BAR;
    QUAD(0)
    BAR;
    RD_A(af, At0, 1)
    stage(B, n0, sB1, T2, 0, buf + 32768);
    asm volatile("s_waitcnt vmcnt(10)" ::: "memory");
    BAR;
    QUAD(1)
    BAR;
    RD_B(bfv, Bt1)
    RD_A(af, At1, 0)
    stage(A, m0, sA1, T2, 0, buf + 0);
    BAR;
    QUAD(0)
    BAR;
    RD_A(af, At1, 1)
    stage(B, n0, sB1, T2, 1, buf + 49152);
    asm volatile("s_waitcnt vmcnt(10)" ::: "memory");
    BAR;
    QUAD(1)
    BAR;
  }
#undef RD_B
#undef RD_A
#undef QUAD
}

// ---------------- f32 -> bf16 conversion: x + small weights only ------------
__global__ __launch_bounds__(256) void cvt_all(
    const float* __restrict__ x, const float* __restrict__ Wq,
    const float* __restrict__ Wk, const float* __restrict__ Wv,
    const float* __restrict__ Wo, u16* __restrict__ xb, u16* __restrict__ wqkv,
    u16* __restrict__ wob) {
  const int i = blockIdx.x * 256 + threadIdx.x;
  const float* s;
  u16* d;
  int off;
  if (i < 2097152) {
    s = x; d = xb; off = i;
  } else {
    const int j = i - 2097152, sel = j >> 17;
    off = j & 131071;
    if (sel == 0)      { s = Wq; d = wqkv; }
    else if (sel == 1) { s = Wk; d = wqkv + 1048576; }
    else if (sel == 2) { s = Wv; d = wqkv + 2097152; }
    else               { s = Wo; d = wob; }
  }
  const size_t e = (size_t)off * 8;
  const float4 a = *(const float4*)(s + e);
  const float4 b = *(const float4*)(s + e + 4);
  u16x8 o;
  o[0] = f2bf(a.x); o[1] = f2bf(a.y); o[2] = f2bf(a.z); o[3] = f2bf(a.w);
  o[4] = f2bf(b.x); o[5] = f2bf(b.y); o[6] = f2bf(b.z); o[7] = f2bf(b.w);
  *(u16x8*)(d + e) = o;
}

// ---------------- merged Q + K/V projection GEMM (R9 pipe) ----------------
__global__ __launch_bounds__(512, 2) void gemm_qkv(const u16* __restrict__ xb,
                                                   const u16* __restrict__ wqkv,
                                                   u16* __restrict__ Qd,
                                                   u16* __restrict__ KTd,
                                                   u16* __restrict__ VTd) {
  __shared__ u16 sm[65536];
  const int tid = threadIdx.x, w = tid >> 6, l = tid & 63, g = l >> 4, r = l & 15;
  const int wr = w >> 2, wc = w & 3;
  f32x4 acc[8][4] = {};
  if (blockIdx.x < 512) {
    const int wg = xcd_swz(blockIdx.x, 512);
    const int m0 = (wg & 7) * 256, n0 = (wg >> 3) * 256;
    gemm256_pipe(wqkv + 1048576, xb, m0, n0, 65536, 65536, 1024, 0, acc, (char*)sm);
#pragma unroll
    for (int m = 0; m < 8; ++m)
#pragma unroll
      for (int n = 0; n < 4; ++n)
#pragma unroll
        for (int j = 0; j < 4; ++j) {
          const int mm = m0 + wr * 128 + m * 16 + g * 4 + j;  // (which,h,d)
          const int nn = n0 + wc * 64 + n * 16 + r;           // (b,s)
          const int which = mm >> 10, hd = mm & 1023, h = hd >> 6, d = hd & 63;
          const int b = nn >> 12, s = nn & 4095;
          u16* dst = which ? VTd : KTd;
          dst[(((size_t)(b * 16 + h)) * 64 + d) * 4096 + s] = f2bf(acc[m][n][j]);
        }
  } else {
    const int wg = xcd_swz(blockIdx.x - 512, 256);
    const int m0 = (wg >> 2) * 256, n0 = (wg & 3) * 256;
    gemm256_pipe(xb, wqkv, m0, n0, 65536, 65536, 1024, 0, acc, (char*)sm);
#pragma unroll
    for (int m = 0; m < 8; ++m)
#pragma unroll
      for (int n = 0; n < 4; ++n)
#pragma unroll
        for (int j = 0; j < 4; ++j) {
          const int mm = m0 + wr * 128 + m * 16 + g * 4 + j;  // (b,s)
          const int nn = n0 + wc * 64 + n * 16 + r;           // (h,d)
          const int b = mm >> 12, s = mm & 4095, h = nn >> 6, d = nn & 63;
          Qd[(((size_t)(b * 16 + h)) * 4096 + s) * 64 + d] =
              f2bf(acc[m][n][j] * 0.125f);
        }
  }
}

// ---------------- final output projection (R9 pipe) ----------------
__global__ __launch_bounds__(512, 2) void gemm_out(const u16* __restrict__ A,
                                                   const u16* __restrict__ BT,
                                                   const float* __restrict__ bo,
                                                   float* __restrict__ out) {
  __shared__ u16 sm[65536];
  const int wg = xcd_swz(blockIdx.x, 256);
  const int m0 = (wg >> 2) * 256, n0 = (wg & 3) * 256;
  const int tid = threadIdx.x, w = tid >> 6, l = tid & 63, g = l >> 4, r = l & 15;
  const int wr = w >> 2, wc = w & 3;
  f32x4 acc[8][4] = {};
  gemm256_pipe(A, BT, m0, n0, 65536, 65536, 1024, 0, acc, (char*)sm);
#pragma unroll
  for (int m = 0; m < 8; ++m)
#pragma unroll
    for (int n = 0; n < 4; ++n)
#pragma unroll
      for (int j = 0; j < 4; ++j) {
        const int mm = m0 + wr * 128 + m * 16 + g * 4 + j;
        const int nn = n0 + wc * 64 + n * 16 + r;
        out[(size_t)mm * 1024 + nn] = acc[m][n][j] + bo[nn];
      }
}

// ---------------- E/F projections: fp32 weights direct, split-K x8 ----------
__global__ __launch_bounds__(512, 2) void gemm_small(const float* __restrict__ WeF,
                                                     const float* __restrict__ WfF,
                                                     const u16* __restrict__ KT,
                                                     const u16* __restrict__ VT,
                                                     float* __restrict__ part) {
  __shared__ u16 sm[65536];
  char* smc = (char*)sm;
  const int bx = blockIdx.x;
  const int h = bx & 15, mode = (bx >> 4) & 1, chunk = bx >> 5;
  const float* Wp = (mode == 0 ? WeF : WfF) + (size_t)h * 1048576;
  const u16* Gp = (mode == 0 ? KT : VT) + (size_t)h * 262144;
  const int tid = threadIdx.x, w = tid >> 6, l = tid & 63, g = l >> 4, r = l & 15;
  const int wr = w >> 2, wc = w & 3;
  const int xc = (tid & 7) ^ ((tid >> 3) & 7);
  const int aR = tid >> 1;
  const int aS0 = (tid & 1) * 4;

  auto stageX = [&](int kt, int buf) {
#pragma unroll
    for (int i = 0; i < 4; ++i) {
      const int row = i * 64 + (tid >> 3);
      const int b = row >> 6, d = row & 63;
      gload16(Gp + (size_t)b * 4194304 + (size_t)d * 4096 + kt * 64 + xc * 8,
              smc + buf * 65536 + i * 8192 + tid * 16);
    }
  };
  float4 aw[8];
  auto loadY = [&](int kt) {
#pragma unroll
    for (int q = 0; q < 4; ++q) {
      const float* p = Wp + (size_t)aR * 4096 + kt * 64 + (aS0 + q) * 8;
      aw[q * 2 + 0] = *(const float4*)(p);
      aw[q * 2 + 1] = *(const float4*)(p + 4);
    }
  };
  auto writeY = [&](int buf) {
#pragma unroll
    for (int q = 0; q < 4; ++q) {
      const float* f0 = (const float*)&aw[q * 2];
      const float* f1 = (const float*)&aw[q * 2 + 1];
      u16x8 o;
#pragma unroll
      for (int e = 0; e < 4; ++e) {
        o[e] = f2bf(f0[e]);
        o[e + 4] = f2bf(f1[e]);
      }
      *(u16x8*)(smc + buf * 65536 + 32768 + aR * 128 +
                (((aS0 + q) ^ (aR & 7)) << 4)) = o;
    }
  };

  f32x4 acc[8][4] = {};
  auto compute = [&](int buf) {
    const char* X = smc + buf * 65536;
    const char* Y = X + 32768;
    const char* Ar = (mode == 0) ? Y : X;
    const char* Br = (mode == 0) ? X : Y;
#pragma unroll
    for (int kk = 0; kk < 2; ++kk) {
      bf16x8 af[8], bfv[4];
#pragma unroll
      for (int n = 0; n < 4; ++n) {
        const int row = wc * 64 + n * 16 + r;
        bfv[n] = *(const bf16x8*)(Br + row * 128 + (((kk * 4 + g) ^ (r & 7)) << 4));
      }
#pragma unroll
      for (int m = 0; m < 8; ++m) {
        const int row = wr * 128 + m * 16 + r;
        af[m] = *(const bf16x8*)(Ar + row * 128 + (((kk * 4 + g) ^ (r & 7)) << 4));
      }
      __builtin_amdgcn_s_setprio(1);
#pragma unroll
      for (int m = 0; m < 8; ++m)
#pragma unroll
        for (int n = 0; n < 4; ++n)
          acc[m][n] = MFMA16(af[m], bfv[n], acc[m][n]);
      __builtin_amdgcn_s_setprio(0);
    }
  };

  const int kt0 = chunk * 8;
  stageX(kt0, 0);
  loadY(kt0);
  asm volatile("s_waitcnt vmcnt(0)" ::: "memory");
  writeY(0);
  __syncthreads();
  for (int t = 0; t < 8; ++t) {
    const int buf = t & 1;
    if (t < 7) {
      stageX(kt0 + t + 1, buf ^ 1);
      loadY(kt0 + t + 1);
    }
    compute(buf);
    if (t < 7) {
      asm volatile("s_waitcnt vmcnt(0)" ::: "memory");
      writeY(buf ^ 1);
    }
    __syncthreads();
  }

  float* Cp = part + ((size_t)((mode * 8 + chunk) * 16 + h)) * 65536;
#pragma unroll
  for (int m = 0; m < 8; ++m)
#pragma unroll
    for (int n = 0; n < 4; ++n)
#pragma unroll
      for (int j = 0; j < 4; ++j)
        Cp[(size_t)(wr * 128 + m * 16 + g * 4 + j) * 256 + wc * 64 + n * 16 + r] =
            acc[m][n][j];
}

// ---------------- reduce split-K x8 partials -> bf16 Kp / VpT ----------------
__global__ __launch_bounds__(256) void reduce_small(const float* __restrict__ part,
                                                    u16* __restrict__ Kp,
                                                    u16* __restrict__ VpT) {
  const int i = blockIdx.x * 256 + threadIdx.x;
  const int mode = i >> 18;
  const int rem = i & 262143;
  const int h = rem >> 14;
  const int e = (rem & 16383) * 4;
  const int m = e >> 8, n = e & 255;
  const float* pb = part + ((size_t)mode * 128 + h) * 65536 + e;
  float4 acc = *(const float4*)(pb);
#pragma unroll
  for (int c = 1; c < 8; ++c) {
    const float4 s = *(const float4*)(pb + (size_t)c * 1048576);
    acc.x += s.x; acc.y += s.y; acc.z += s.z; acc.w += s.w;
  }
  ushort4 o;
  o.x = f2bf(acc.x); o.y = f2bf(acc.y); o.z = f2bf(acc.z); o.w = f2bf(acc.w);
  if (mode == 0) {
    const int b = n >> 6, d = n & 63;
    *(ushort4*)(Kp + ((size_t)(b * 16 + h)) * 16384 + m * 64 + d) = o;
  } else {
    const int b = m >> 6, d = m & 63;
    *(ushort4*)(VpT + ((size_t)(b * 16 + h)) * 16384 + d * 256 + n) = o;
  }
}

// ---------------- fused scores + softmax + PV ----------------
__global__ __launch_bounds__(256, 1) void attn_fused(const u16* __restrict__ Q,
                                                     const u16* __restrict__ Kp,
                                                     const u16* __restrict__ VpT,
                                                     u16* __restrict__ att) {
  __shared__ u16 P[4][16 * 264];
  const int gid = blockIdx.x;
  const int bh = gid >> 3;
  const int st = gid & 7;
  const int hh = bh & 15, b = bh >> 4;
  const int tid = threadIdx.x, w = tid >> 6, l = tid & 63, g = l >> 4, r = l & 15;
  const u16* Kpb = Kp + (size_t)bh * 256 * 64;
  const u16* Vb = VpT + (size_t)bh * 64 * 256;

  bf16x8 kf[32];
  bf16x8 vf[32];
#pragma unroll
  for (int fn = 0; fn < 16; ++fn) {
    kf[fn * 2 + 0] = ldf(Kpb + (fn * 16 + r) * 64 + g * 8);
    kf[fn * 2 + 1] = ldf(Kpb + (fn * 16 + r) * 64 + 32 + g * 8);
  }
#pragma unroll
  for (int fn2 = 0; fn2 < 4; ++fn2)
#pragma unroll
    for (int kk = 0; kk < 8; ++kk)
      vf[fn2 * 8 + kk] = ldf(Vb + (fn2 * 16 + r) * 256 + kk * 32 + g * 8);

  u16* Pw = P[w];
  for (int t = 0; t < 8; ++t) {
    const int s0 = st * 512 + t * 64 + w * 16;
    const u16* Qb = Q + ((size_t)bh * 4096 + s0) * 64;
    const bf16x8 qf0 = ldf(Qb + r * 64 + g * 8);
    const bf16x8 qf1 = ldf(Qb + r * 64 + 32 + g * 8);
    f32x4 sc[16];
#pragma unroll
    for (int fn = 0; fn < 16; ++fn) {
      sc[fn] = MFMA16(qf0, kf[fn * 2 + 0], (f32x4){});
      sc[fn] = MFMA16(qf1, kf[fn * 2 + 1], sc[fn]);
    }
    float rinv[4];
#pragma unroll
    for (int j = 0; j < 4; ++j) {
      float sum = 0.f;
#pragma unroll
      for (int fn = 0; fn < 16; ++fn) {
        const float e = __expf(sc[fn][j]);
        sc[fn][j] = e;
        sum += e;
      }
      sum += __shfl_xor(sum, 1);
      sum += __shfl_xor(sum, 2);
      sum += __shfl_xor(sum, 4);
      sum += __shfl_xor(sum, 8);
      rinv[j] = 1.0f / sum;
    }
#pragma unroll
    for (int fn = 0; fn < 16; ++fn)
#pragma unroll
      for (int j = 0; j < 4; ++j)
        Pw[(g * 4 + j) * 264 + fn * 16 + r] = f2bf(sc[fn][j]);

    f32x4 o[4] = {};
#pragma unroll
    for (int kk = 0; kk < 8; ++kk) {
      const bf16x8 pa = ldf(Pw + r * 264 + kk * 32 + g * 8);
#pragma unroll
      for (int fn2 = 0; fn2 < 4; ++fn2)
        o[fn2] = MFMA16(pa, vf[fn2 * 8 + kk], o[fn2]);
    }
#pragma unroll
    for (int fn2 = 0; fn2 < 4; ++fn2)
#pragma unroll
      for (int j = 0; j < 4; ++j) {
        const int s = s0 + g * 4 + j;
        const int d = fn2 * 16 + r;
        att[((size_t)b * 4096 + s) * 1024 + hh * 64 + d] = f2bf(o[fn2][j] * rinv[j]);
      }
  }
}

extern "C" void kernel_launch(void* const* d_in, const int* in_sizes, int n_in,
                              void* d_out, int out_size, void* d_ws, size_t ws_size,
                              hipStream_t stream) {
  (void)in_sizes; (void)n_in; (void)out_size; (void)ws_size;
  const float* x  = (const float*)d_in[0];
  const float* Wq = (const float*)d_in[1];
  const float* Wk = (const float*)d_in[2];
  const float* Wv = (const float*)d_in[3];
  const float* We = (const float*)d_in[4];
  const float* Wf = (const float*)d_in[5];
  const float* Wo = (const float*)d_in[6];
  const float* bo = (const float*)d_in[7];
  char* ws = (char*)d_ws;
  u16* xb    = (u16*)(ws + 0);           // x bf16 [16384][1024]
  float* prt = (float*)(ws + 0);         // split-K x8 partials (67,108,864 B)
  u16* wqkv  = (u16*)(ws + 33554432);    // Wq|Wk|Wv [3072][1024]
  u16* att   = (u16*)(ws + 73400320);    // attn output [16384][1024] bf16
  u16* wob   = (u16*)(ws + 106954752);   // Wo [1024][1024]
  u16* Qd    = (u16*)(ws + 109051904);   // Q/8 [64][4096][64]
  u16* KTd   = (u16*)(ws + 142606336);   // K^T [64][64][4096]
  u16* VTd   = (u16*)(ws + 176160768);   // V^T [64][64][4096]
  u16* Kpd   = (u16*)(ws + 209715200);   // Kp_t [64][256][64]
  u16* VpTd  = (u16*)(ws + 211812352);   // VpT  [64][64][256]

  cvt_all<<<10240, 256, 0, stream>>>(x, Wq, Wk, Wv, Wo, xb, wqkv, wob);
  gemm_qkv<<<768, 512, 0, stream>>>(xb, wqkv, Qd, KTd, VTd);
  gemm_small<<<256, 512, 0, stream>>>(We, Wf, KTd, VTd, prt);
  reduce_small<<<2048, 256, 0, stream>>>(prt, Kpd, VpTd);
  attn_fused<<<512, 256, 0, stream>>>(Qd, Kpd, VpTd, att);
  gemm_out<<<256, 512, 0, stream>>>(att, wob, bo, (float*)d_out);
}